// Round 1
// baseline (497.174 us; speedup 1.0000x reference)
//
#include <hip/hip_runtime.h>
#include <hip/hip_bf16.h>

#define NN 8192
#define DD 128
#define DQK 256
#define EE 262144
#define EDGE_DIM 50
#define HID 32
#define SCALE 0.08838834764831845f  // 1/sqrt(128)

using f32x4 = __attribute__((ext_vector_type(4))) float;
using f32x2 = __attribute__((ext_vector_type(2))) float;
using bf16x8 = __attribute__((ext_vector_type(8))) short;  // 8 bf16 = 4 VGPRs
using s16x4 = __attribute__((ext_vector_type(4))) short;

static __device__ __forceinline__ short f2b(float f) {
  __hip_bfloat16 h = __float2bfloat16(f);
  return __builtin_bit_cast(short, h);
}
static __device__ __forceinline__ float b2f(short s) {
  unsigned u = ((unsigned)(unsigned short)s) << 16;
  return __builtin_bit_cast(float, u);
}

// ---------------- K1a: QK[n][0:128]=mag*cos, [128:256]=mag*sin (bf16) --------
__global__ void k1a_qk(const float* __restrict__ mag, const float* __restrict__ phase,
                       short* __restrict__ qkb) {
  int t = blockIdx.x * 256 + threadIdx.x;   // 0..N*128-1
  int n = t >> 7, d = t & 127;
  float m = mag[t], p = phase[t];
  float sn, cs;
  __sincosf(p, &sn, &cs);
  qkb[n * DQK + d] = f2b(m * cs);
  qkb[n * DQK + 128 + d] = f2b(m * sn);
}

// ---------------- K1b: VT[f][n] = V[n][f], V=[mag|phase], bf16 ---------------
__global__ void k1b_vt(const float* __restrict__ mag, const float* __restrict__ phase,
                       short* __restrict__ vtb) {
  __shared__ float tile[64][65];
  int bn = blockIdx.x;   // 0..127 node tile
  int bd = blockIdx.y;   // 0..1 feature tile
  int sel = blockIdx.z;  // 0 mag, 1 phase
  const float* src = sel ? phase : mag;
  int t = threadIdx.x;
#pragma unroll
  for (int rep = 0; rep < 16; ++rep) {
    int idx = rep * 256 + t;
    int r = idx >> 6, c = idx & 63;  // r = local n, c = local d
    tile[r][c] = src[(size_t)(bn * 64 + r) * DD + bd * 64 + c];
  }
  __syncthreads();
#pragma unroll
  for (int rep = 0; rep < 16; ++rep) {
    int idx = rep * 256 + t;
    int r = idx >> 6, c = idx & 63;  // r = local d, c = local n
    vtb[(size_t)(sel * 128 + bd * 64 + r) * NN + bn * 64 + c] = f2b(tile[c][r]);
  }
}

// ---------------- K2: edge MLP bias + row histogram --------------------------
__global__ __launch_bounds__(256) void k2_mlp(
    const float* __restrict__ rbf, const float* __restrict__ W1,
    const float* __restrict__ b1, const float* __restrict__ W2,
    const float* __restrict__ b2, const int* __restrict__ eidx,
    float* __restrict__ bias, int* __restrict__ cnt) {
  __shared__ alignas(16) float w1s[EDGE_DIM * HID];
  __shared__ alignas(16) float b1s[HID];
  __shared__ alignas(16) float w2s[HID];
  __shared__ float b2s;
  int tid = threadIdx.x;
  for (int k = tid; k < EDGE_DIM * HID; k += 256) w1s[k] = W1[k];
  if (tid < HID) { b1s[tid] = b1[tid]; w2s[tid] = W2[tid]; }
  if (tid == 0) b2s = b2[0];
  __syncthreads();
  int e = blockIdx.x * 256 + tid;
  const f32x2* r2 = reinterpret_cast<const f32x2*>(rbf + (size_t)e * EDGE_DIM);
  f32x2 rr[25];
#pragma unroll
  for (int k = 0; k < 25; ++k) rr[k] = r2[k];
  f32x4 h[8];
#pragma unroll
  for (int jj = 0; jj < 8; ++jj) h[jj] = reinterpret_cast<const f32x4*>(b1s)[jj];
#pragma unroll
  for (int k = 0; k < 25; ++k) {
    const f32x4* w0 = reinterpret_cast<const f32x4*>(w1s + (2 * k) * HID);
    const f32x4* w1r = reinterpret_cast<const f32x4*>(w1s + (2 * k + 1) * HID);
#pragma unroll
    for (int jj = 0; jj < 8; ++jj) h[jj] += rr[k].x * w0[jj] + rr[k].y * w1r[jj];
  }
  float outv = b2s;
#pragma unroll
  for (int jj = 0; jj < 8; ++jj) {
    f32x4 x = h[jj];
    f32x4 sl;
#pragma unroll
    for (int q = 0; q < 4; ++q) sl[q] = x[q] / (1.0f + __expf(-x[q]));
    f32x4 pr = sl * reinterpret_cast<const f32x4*>(w2s)[jj];
    outv += pr.x + pr.y + pr.z + pr.w;
  }
  bias[e] = outv;
  atomicAdd(&cnt[eidx[e]], 1);
}

// ---------------- K3: exclusive scan of counts -> rowptr, cursor -------------
__global__ __launch_bounds__(1024) void k3_scan(const int* __restrict__ cnt,
                                                int* __restrict__ rowptr,
                                                int* __restrict__ cursor) {
  __shared__ int sums[1024];
  int t = threadIdx.x;
  int v[8];
  int loc = 0;
#pragma unroll
  for (int k = 0; k < 8; ++k) { v[k] = cnt[t * 8 + k]; loc += v[k]; }
  sums[t] = loc;
  __syncthreads();
  for (int off = 1; off < 1024; off <<= 1) {
    int x = (t >= off) ? sums[t - off] : 0;
    __syncthreads();
    sums[t] += x;
    __syncthreads();
  }
  int excl = sums[t] - loc;
#pragma unroll
  for (int k = 0; k < 8; ++k) {
    rowptr[t * 8 + k] = excl;
    cursor[t * 8 + k] = excl;
    excl += v[k];
  }
  if (t == 1023) rowptr[NN] = excl;
}

// ---------------- K4: scatter edge ids into CSR slots ------------------------
__global__ void k4_scatter(const int* __restrict__ eidx, int* __restrict__ cursor,
                           int* __restrict__ slot) {
  int e = blockIdx.x * 256 + threadIdx.x;
  int i = eidx[e];
  int p = atomicAdd(&cursor[i], 1);
  slot[p] = e;
}

// ---------------- K5: fused dense flash (no max needed) ----------------------
// grid = 512: (row-block rb of 32 rows) x (col half of 4096). BN=256 chunks.
constexpr int BM = 32;
constexpr int BN = 256;
constexpr int HALF_COLS = 4096;
constexpr int NCHUNK = HALF_COLS / BN;  // 16
constexpr int PPITCH = 264;             // shorts per LDS P row (+8 pad)

__global__ __launch_bounds__(256, 2) void k5_flash(
    const short* __restrict__ qk,  // [N][256] bf16
    const short* __restrict__ vt,  // [256][N] bf16
    float* __restrict__ nump,      // [2][N][256]
    float* __restrict__ denp) {    // [2][N]
  __shared__ short plds[BM * PPITCH];
  __shared__ float dlds[4][BM];
  int rb = blockIdx.x >> 1;
  int half = blockIdx.x & 1;
  int tid = threadIdx.x;
  int wave = tid >> 6;
  int lane = tid & 63;
  int l15 = lane & 15;
  int quad = lane >> 4;
  int r0 = rb * BM;

  // Q fragments resident in registers: A[m=l15][k=quad*8+j], per rowtile/kstep
  bf16x8 qf[2][8];
#pragma unroll
  for (int rt = 0; rt < 2; ++rt) {
    const bf16x8* qrow =
        reinterpret_cast<const bf16x8*>(qk + (size_t)(r0 + rt * 16 + l15) * DQK);
#pragma unroll
    for (int ks = 0; ks < 8; ++ks) qf[rt][ks] = qrow[ks * 4 + quad];
  }
  f32x4 acc[2][4] = {};  // [rowtile][feature-tile]
  float den[2][4] = {};  // [rowtile][reg-row]

  int cbase_half = half * HALF_COLS;
  for (int ch = 0; ch < NCHUNK; ++ch) {
    int c0 = cbase_half + ch * BN;
    int cw = c0 + wave * 64;  // this wave's 64 S-columns
    // ---- QK^T: S strip 32x64 ----
    f32x4 s[2][4] = {};
#pragma unroll
    for (int ks = 0; ks < 8; ++ks) {
      bf16x8 kf[4];
#pragma unroll
      for (int ct = 0; ct < 4; ++ct) {
        int col = cw + ct * 16 + l15;
        kf[ct] = *reinterpret_cast<const bf16x8*>(qk + (size_t)col * DQK + ks * 32 +
                                                  quad * 8);
      }
#pragma unroll
      for (int ct = 0; ct < 4; ++ct)
#pragma unroll
        for (int rt = 0; rt < 2; ++rt)
          s[rt][ct] = __builtin_amdgcn_mfma_f32_16x16x32_bf16(qf[rt][ks], kf[ct],
                                                              s[rt][ct], 0, 0, 0);
    }
    // ---- exp + den accumulate + P -> LDS (C layout: row=quad*4+r, col=l15) --
    __syncthreads();  // previous chunk's P reads done before overwrite
#pragma unroll
    for (int rt = 0; rt < 2; ++rt)
#pragma unroll
      for (int ct = 0; ct < 4; ++ct)
#pragma unroll
        for (int r = 0; r < 4; ++r) {
          float p = __expf(s[rt][ct][r] * SCALE);
          den[rt][r] += p;
          int row = rt * 16 + quad * 4 + r;
          int col = wave * 64 + ct * 16 + l15;
          plds[row * PPITCH + col] = f2b(p);
        }
    __syncthreads();
    // ---- PV: this wave computes features wave*64..+63, K over 256 cols ------
#pragma unroll
    for (int ks = 0; ks < 8; ++ks) {
      bf16x8 pa[2];
#pragma unroll
      for (int rt = 0; rt < 2; ++rt)
        pa[rt] = *reinterpret_cast<const bf16x8*>(plds + (rt * 16 + l15) * PPITCH +
                                                  ks * 32 + quad * 8);
#pragma unroll
      for (int ft = 0; ft < 4; ++ft) {
        int feat = wave * 64 + ft * 16 + l15;
        bf16x8 vb = *reinterpret_cast<const bf16x8*>(vt + (size_t)feat * NN + c0 +
                                                     ks * 32 + quad * 8);
#pragma unroll
        for (int rt = 0; rt < 2; ++rt)
          acc[rt][ft] = __builtin_amdgcn_mfma_f32_16x16x32_bf16(pa[rt], vb,
                                                                acc[rt][ft], 0, 0, 0);
      }
    }
  }
  // ---- write partial num ----
  float* npB = nump + (size_t)half * NN * DQK;
#pragma unroll
  for (int rt = 0; rt < 2; ++rt)
#pragma unroll
    for (int ft = 0; ft < 4; ++ft) {
      int row = r0 + rt * 16 + quad * 4;
      int feat = wave * 64 + ft * 16 + l15;
#pragma unroll
      for (int r = 0; r < 4; ++r) npB[(size_t)(row + r) * DQK + feat] = acc[rt][ft][r];
    }
  // ---- reduce den across 16 lanes of quad, then across waves ----
#pragma unroll
  for (int rt = 0; rt < 2; ++rt)
#pragma unroll
    for (int r = 0; r < 4; ++r) {
      float d = den[rt][r];
      d += __shfl_xor(d, 1);
      d += __shfl_xor(d, 2);
      d += __shfl_xor(d, 4);
      d += __shfl_xor(d, 8);
      if (l15 == 0) dlds[wave][rt * 16 + quad * 4 + r] = d;
    }
  __syncthreads();
  if (tid < BM) {
    float d = dlds[0][tid] + dlds[1][tid] + dlds[2][tid] + dlds[3][tid];
    denp[half * NN + r0 + tid] = d;
  }
}

// ---------------- K6: per-row sparse correction + combine + normalize --------
__global__ __launch_bounds__(64) void k6_combine(
    const int* __restrict__ eidx, const float* __restrict__ bias,
    const int* __restrict__ rowptr, const int* __restrict__ slot,
    const short* __restrict__ qk, const float* __restrict__ mag,
    const float* __restrict__ phase, const float* __restrict__ nump,
    const float* __restrict__ denp, float* __restrict__ out) {
  __shared__ int js[1024];
  __shared__ float bs[1024];
  __shared__ int keepf[1024];
  int i = blockIdx.x;
  int lane = threadIdx.x;
  int start = rowptr[i];
  int cnt = rowptr[i + 1] - start;
  if (cnt > 1024) cnt = 1024;  // Poisson(32): unreachable in practice
  for (int p = lane; p < cnt; p += 64) {
    int eid = slot[start + p];
    js[p] = eidx[EE + eid];
    bs[p] = bias[eid];
  }
  __syncthreads();
  // exact duplicate-(i,j) merge: first occurrence keeps summed beta
  for (int base = 0; base < cnt; base += 64) {
    int p = base + lane;
    float bsum = 0.f;
    int keep = 0;
    if (p < cnt) {
      int j = js[p];
      bsum = bs[p];
      keep = 1;
      for (int q = 0; q < cnt; ++q) {
        if (q == p || js[q] != j) continue;
        if (q < p) { keep = 0; break; }
        bsum += bs[q];
      }
    }
    __syncthreads();
    if (p < cnt) { bs[p] = bsum; keepf[p] = keep; }
    __syncthreads();
  }
  // q_i fragment: 4 features per lane
  f32x4 qi;
  {
    s16x4 qv = *reinterpret_cast<const s16x4*>(qk + (size_t)i * DQK + lane * 4);
#pragma unroll
    for (int q = 0; q < 4; ++q) qi[q] = b2f(qv[q]);
  }
  f32x4 nc = {0.f, 0.f, 0.f, 0.f};
  float denc = 0.f;
  for (int p = 0; p < cnt; ++p) {
    if (!keepf[p]) continue;
    int j = js[p];
    s16x4 kv = *reinterpret_cast<const s16x4*>(qk + (size_t)j * DQK + lane * 4);
    float sp = qi[0] * b2f(kv[0]) + qi[1] * b2f(kv[1]) + qi[2] * b2f(kv[2]) +
               qi[3] * b2f(kv[3]);
    sp += __shfl_xor(sp, 1);
    sp += __shfl_xor(sp, 2);
    sp += __shfl_xor(sp, 4);
    sp += __shfl_xor(sp, 8);
    sp += __shfl_xor(sp, 16);
    sp += __shfl_xor(sp, 32);
    float delta = __expf(sp * SCALE) * expm1f(bs[p]);
    denc += delta;
    f32x4 v = (lane < 32)
                  ? *reinterpret_cast<const f32x4*>(mag + (size_t)j * DD + 4 * lane)
                  : *reinterpret_cast<const f32x4*>(phase + (size_t)j * DD + 4 * lane -
                                                    128);
    nc += delta * v;
  }
  f32x4 nd = *reinterpret_cast<const f32x4*>(nump + (size_t)i * DQK + 4 * lane) +
             *reinterpret_cast<const f32x4*>(nump + (size_t)(NN + i) * DQK + 4 * lane);
  float den = denp[i] + denp[NN + i] + denc;
  f32x4 res = (nd + nc) * (1.0f / den);
  if (lane < 32)
    *reinterpret_cast<f32x4*>(out + (size_t)i * DD + 4 * lane) = res;
  else
    *reinterpret_cast<f32x4*>(out + (size_t)NN * DD + (size_t)i * DD + 4 * lane - 128) =
        res;
}

// ---------------- workspace layout -------------------------------------------
constexpr size_t OFF_QK = 0;                                   // 4 MiB bf16
constexpr size_t OFF_VT = (size_t)NN * DQK * 2;                // 4 MiB bf16
constexpr size_t OFF_BIAS = OFF_VT + (size_t)DQK * NN * 2;     // 1 MiB f32
constexpr size_t OFF_CNT = OFF_BIAS + (size_t)EE * 4;
constexpr size_t OFF_ROWPTR = OFF_CNT + (size_t)NN * 4;
constexpr size_t OFF_CURSOR = OFF_ROWPTR + (size_t)(NN + 2) * 4;
constexpr size_t OFF_SLOT = OFF_CURSOR + (size_t)NN * 4;
constexpr size_t OFF_NUMP = (OFF_SLOT + (size_t)EE * 4 + 255) & ~(size_t)255;
constexpr size_t OFF_DENP = OFF_NUMP + 2ull * NN * DQK * 4;
constexpr size_t WS_NEED = OFF_DENP + 2ull * NN * 4;

extern "C" void kernel_launch(void* const* d_in, const int* in_sizes, int n_in,
                              void* d_out, int out_size, void* d_ws, size_t ws_size,
                              hipStream_t stream) {
  const float* mag = (const float*)d_in[0];
  const float* phase = (const float*)d_in[1];
  const int* eidx = (const int*)d_in[2];
  const float* rbf = (const float*)d_in[3];
  const float* W1 = (const float*)d_in[4];
  const float* b1 = (const float*)d_in[5];
  const float* W2 = (const float*)d_in[6];
  const float* b2 = (const float*)d_in[7];
  float* out = (float*)d_out;
  char* ws = (char*)d_ws;
  if (ws_size < WS_NEED) return;  // ~27.5 MiB required

  short* qkb = (short*)(ws + OFF_QK);
  short* vtb = (short*)(ws + OFF_VT);
  float* bias = (float*)(ws + OFF_BIAS);
  int* cnt = (int*)(ws + OFF_CNT);
  int* rowptr = (int*)(ws + OFF_ROWPTR);
  int* cursor = (int*)(ws + OFF_CURSOR);
  int* slot = (int*)(ws + OFF_SLOT);
  float* nump = (float*)(ws + OFF_NUMP);
  float* denp = (float*)(ws + OFF_DENP);

  hipMemsetAsync(cnt, 0, (size_t)NN * 4, stream);
  k1a_qk<<<NN * DD / 256, 256, 0, stream>>>(mag, phase, qkb);
  k1b_vt<<<dim3(NN / 64, DD / 64, 2), 256, 0, stream>>>(mag, phase, vtb);
  k2_mlp<<<EE / 256, 256, 0, stream>>>(rbf, W1, b1, W2, b2, eidx, bias, cnt);
  k3_scan<<<1, 1024, 0, stream>>>(cnt, rowptr, cursor);
  k4_scatter<<<EE / 256, 256, 0, stream>>>(eidx, cursor, slot);
  k5_flash<<<(NN / BM) * 2, 256, 0, stream>>>(qkb, vtb, nump, denp);
  k6_combine<<<NN, 64, 0, stream>>>(eidx, bias, rowptr, slot, qkb, mag, phase, nump,
                                    denp, out);
}